// Round 9
// baseline (1310.435 us; speedup 1.0000x reference)
//
#include <hip/hip_runtime.h>

// ---- static config ----
static constexpr int NN   = 128;   // dialogues
static constexpr int LL   = 64;    // utterance length
static constexpr int KWIN = 40;
static constexpr int KEFF = 40;
static constexpr int NQ   = 127;   // N-1
static constexpr int NCLS = 6;
static constexpr int KP   = 320;   // padded K for MFMA GEMMs (300 -> 320)

// GRU scans: 39 chunks = 10 LDS-resident + 29 streamed (ring depth 8)
// att scans: 40 chunks = 16 LDS-resident + 24 streamed (ring depth 8)
static constexpr int GRU_RES = 10;
static constexpr int ATT_RES = 16;
static constexpr size_t GRU_LDS = (size_t)GRU_RES * 912 * 16 + (304 + 2700) * 4;                 // 157,936
static constexpr size_t ATT_LDS = (size_t)ATT_RES * 608 * 16 + (320 + 1216 + 304 + 40 + 40) * 4; // 163,328

typedef __attribute__((ext_vector_type(8))) short short8;
typedef __attribute__((ext_vector_type(4))) float floatx4;

__device__ __forceinline__ float sigm(float x) { return 1.f / (1.f + __expf(-x)); }
__device__ __forceinline__ short f2bf(float f) {
    unsigned x = __float_as_uint(f);
    unsigned r = (x + 0x7fffu + ((x >> 16) & 1u)) >> 16;
    return (short)r;
}
__device__ __forceinline__ float b2f(short u) {
    return __uint_as_float(((unsigned)(unsigned short)u) << 16);
}
__device__ __forceinline__ void bfp(unsigned v, float& lo, float& hi) {
    lo = __uint_as_float(v << 16);
    hi = __uint_as_float(v & 0xffff0000u);
}
__device__ __forceinline__ void dot8(uint4 wv, float4 h0, float4 h1, float& acc) {
    float l0, u0, l1, u1, l2, u2, l3, u3;
    bfp(wv.x, l0, u0); bfp(wv.y, l1, u1);
    bfp(wv.z, l2, u2); bfp(wv.w, l3, u3);
    acc = fmaf(l0, h0.x, acc); acc = fmaf(u0, h0.y, acc);
    acc = fmaf(l1, h0.z, acc); acc = fmaf(u1, h0.w, acc);
    acc = fmaf(l2, h1.x, acc); acc = fmaf(u2, h1.y, acc);
    acc = fmaf(l3, h1.z, acc); acc = fmaf(u3, h1.w, acc);
}

// ---------------------------------------------------------------------------
// 4 fused f32 [1800][300] -> bf16 [1800][320] conversions (blockIdx.y selects)
// ---------------------------------------------------------------------------
__global__ void k_conv4(const float* __restrict__ s0, const float* __restrict__ s1,
                        const float* __restrict__ s2, const float* __restrict__ s3,
                        short* __restrict__ d0, short* __restrict__ d1,
                        short* __restrict__ d2, short* __restrict__ d3)
{
    int which = blockIdx.y;
    const float* s = (which == 0) ? s0 : (which == 1) ? s1 : (which == 2) ? s2 : s3;
    short* d = (which == 0) ? d0 : (which == 1) ? d1 : (which == 2) ? d2 : d3;
    int r = blockIdx.x, e = threadIdx.x;   // 320 threads
    float v = (e < 300) ? s[(size_t)r * 300 + e] : 0.f;
    d[(size_t)r * KP + e] = f2bf(v);
}

// ---------------------------------------------------------------------------
// Pack GRU Whh [2][900][300] f32 -> chunk-interleaved bf16 [2][39][912][8sh]
// Fused for both GRUs (blockIdx.y: 0=utt, 1=ctx).
// ---------------------------------------------------------------------------
__global__ void k_pack_gru2(const float* __restrict__ W0, const float* __restrict__ W1,
                            short* __restrict__ d0, short* __restrict__ d1)
{
    const float* W = blockIdx.y ? W1 : W0;
    short* dst = blockIdx.y ? d1 : d0;
    int idx = blockIdx.x * 256 + threadIdx.x;
    if (idx >= 2 * 39 * 900) return;
    int u = idx % 900, dc = idx / 900;
    int c = dc % 39, d = dc / 39;
    int cs = c / 3, s = c - cs * 3;
    int p = u / 300, m = u - p * 300;
    const float* src = W + ((size_t)d * 900 + s * 300 + m) * 300 + p * 100;
    short8 sv;
#pragma unroll
    for (int i = 0; i < 8; ++i) {
        int cl = cs * 8 + i;
        sv[i] = (cl < 100) ? f2bf(src[cl]) : (short)0;
    }
    *(short8*)(dst + ((size_t)(d * 39 + c) * 912 + u) * 8) = sv;
}

// ---------------------------------------------------------------------------
// Pack attn Ur/Uw [6][300][300] -> [6][40][608][8sh]
// ---------------------------------------------------------------------------
__global__ void k_pack_att(const float* __restrict__ Ur, const float* __restrict__ Uw,
                           short* __restrict__ dst)
{
    int idx = blockIdx.x * 256 + threadIdx.x;
    if (idx >= 6 * 40 * 600) return;
    int u = idx % 600, hc = idx / 600;
    int c = hc % 40, hd = hc / 40;
    int cs = c >> 1, s = c & 1;
    int p = u / 300, m = u - p * 300;
    int lim = p ? 140 : 160;
    const float* src = (s ? Uw : Ur) + ((size_t)hd * 300 + m) * 300 + 160 * p;
    short8 sv;
#pragma unroll
    for (int i = 0; i < 8; ++i) {
        int cl = cs * 8 + i;
        sv[i] = (cl < lim) ? f2bf(src[cl]) : (short)0;
    }
    *(short8*)(dst + ((size_t)(hd * 40 + c) * 608 + u) * 8) = sv;
}

// ---------------------------------------------------------------------------
// MFMA GEMM A-operand loader, 8 bf16 at (row, col offset o).
// MODE 0: A is bf16 [R][320].  MODE 1: gather emb row via ids (row=t*128+n).
// MODE 2: window build from u (row=k*127+q -> u[q+1-KWIN+k], zero if <0).
// ---------------------------------------------------------------------------
template<int MODE>
__device__ __forceinline__ short8 load_a8(const short* __restrict__ Abf,
                                          const float* __restrict__ emb,
                                          const int* __restrict__ ids,
                                          const float* __restrict__ uu,
                                          int row, int R, int o)
{
    short8 z = {0,0,0,0,0,0,0,0};
    if (MODE == 0) {
        if (row < R) return *(const short8*)(Abf + (size_t)row * KP + o);
        return z;
    }
    const float* src;
    if (MODE == 1) {
        int n = row & (NN - 1), t = row >> 7;
        src = emb + (size_t)ids[n * LL + t] * 300;
    } else {
        if (row >= R) return z;
        int k = row / NQ, q = row - k * NQ;
        int s = q + 1 - KWIN + k;
        if (s < 0) return z;
        src = uu + (size_t)s * 300;
    }
    short8 r = z;
    if (o + 8 <= 300) {
        float4 f0 = *(const float4*)(src + o);
        float4 f1 = *(const float4*)(src + o + 4);
        r[0] = f2bf(f0.x); r[1] = f2bf(f0.y); r[2] = f2bf(f0.z); r[3] = f2bf(f0.w);
        r[4] = f2bf(f1.x); r[5] = f2bf(f1.y); r[6] = f2bf(f1.z); r[7] = f2bf(f1.w);
    } else if (o < 300) {
#pragma unroll
        for (int i = 0; i < 8; ++i)
            r[i] = (o + i < 300) ? f2bf(src[o + i]) : (short)0;
    }
    return r;
}

// ---------------------------------------------------------------------------
// bf16 MFMA GEMM (B^T layout), pipelined staging, bf16 output.
// blockIdx.z selects (B,bias,C) vs (B2,bias2,C2) for the fused att-proj pair.
// ---------------------------------------------------------------------------
template<int MODE>
__global__ __launch_bounds__(256)
void k_mgemm(const short* __restrict__ Abf, const float* __restrict__ emb,
             const int* __restrict__ ids, const float* __restrict__ uu,
             const short* __restrict__ B, const float* __restrict__ bias,
             short* __restrict__ C,
             const short* __restrict__ B2, const float* __restrict__ bias2,
             short* __restrict__ C2,
             int R, int Cc)
{
    const short* Bp = blockIdx.z ? B2 : B;
    const float* bp = blockIdx.z ? bias2 : bias;
    short* Cp = blockIdx.z ? C2 : C;
    __shared__ short As[128 * 40];
    __shared__ short Bs[128 * 40];
    const int tid = threadIdx.x;
    const int r0 = blockIdx.y * 128, c0 = blockIdx.x * 128;
    const int w = tid >> 6, lane = tid & 63;
    const int m16 = lane & 15, quad = lane >> 4;
    const int wm = w & 1, wn = w >> 1;
    floatx4 acc[4][4];
#pragma unroll
    for (int i = 0; i < 4; ++i)
#pragma unroll
        for (int j = 0; j < 4; ++j) acc[i][j] = (floatx4){0.f, 0.f, 0.f, 0.f};

    const int ra0 = tid >> 2,         sa0 = tid & 3;
    const int ra1 = (tid + 256) >> 2, sa1 = tid & 3;
    const short8 za = {0,0,0,0,0,0,0,0};
    short8 na0, na1, nb0 = za, nb1 = za;
    na0 = load_a8<MODE>(Abf, emb, ids, uu, r0 + ra0, R, sa0 * 8);
    na1 = load_a8<MODE>(Abf, emb, ids, uu, r0 + ra1, R, sa1 * 8);
    if (c0 + ra0 < Cc) nb0 = *(const short8*)(Bp + (size_t)(c0 + ra0) * KP + sa0 * 8);
    if (c0 + ra1 < Cc) nb1 = *(const short8*)(Bp + (size_t)(c0 + ra1) * KP + sa1 * 8);

#pragma unroll
    for (int it = 0; it < KP / 32; ++it) {
        *(short8*)(As + ra0 * 40 + sa0 * 8) = na0;
        *(short8*)(As + ra1 * 40 + sa1 * 8) = na1;
        *(short8*)(Bs + ra0 * 40 + sa0 * 8) = nb0;
        *(short8*)(Bs + ra1 * 40 + sa1 * 8) = nb1;
        __syncthreads();
        if (it + 1 < KP / 32) {
            const int k0 = (it + 1) * 32;
            na0 = load_a8<MODE>(Abf, emb, ids, uu, r0 + ra0, R, k0 + sa0 * 8);
            na1 = load_a8<MODE>(Abf, emb, ids, uu, r0 + ra1, R, k0 + sa1 * 8);
            nb0 = za; nb1 = za;
            if (c0 + ra0 < Cc) nb0 = *(const short8*)(Bp + (size_t)(c0 + ra0) * KP + k0 + sa0 * 8);
            if (c0 + ra1 < Cc) nb1 = *(const short8*)(Bp + (size_t)(c0 + ra1) * KP + k0 + sa1 * 8);
        }
        short8 af[4], bfr[4];
#pragma unroll
        for (int mt = 0; mt < 4; ++mt)
            af[mt] = *(const short8*)(As + (wm * 64 + mt * 16 + m16) * 40 + quad * 8);
#pragma unroll
        for (int nt = 0; nt < 4; ++nt)
            bfr[nt] = *(const short8*)(Bs + (wn * 64 + nt * 16 + m16) * 40 + quad * 8);
#pragma unroll
        for (int mt = 0; mt < 4; ++mt)
#pragma unroll
            for (int nt = 0; nt < 4; ++nt)
                acc[mt][nt] = __builtin_amdgcn_mfma_f32_16x16x32_bf16(
                    af[mt], bfr[nt], acc[mt][nt], 0, 0, 0);
        __syncthreads();
    }
#pragma unroll
    for (int mt = 0; mt < 4; ++mt) {
#pragma unroll
        for (int nt = 0; nt < 4; ++nt) {
            int col = c0 + wn * 64 + nt * 16 + m16;
            if (col >= Cc) continue;
            float bv = bp ? bp[col] : 0.f;
#pragma unroll
            for (int i = 0; i < 4; ++i) {
                int row = r0 + wm * 64 + mt * 16 + quad * 4 + i;
                if (row < R) Cp[(size_t)row * Cc + col] = f2bf(acc[mt][nt][i] + bv);
            }
        }
    }
}

// ---------------------------------------------------------------------------
// f32 GEMM (small lin layer): C = act(A @ B^T + bias)
// ---------------------------------------------------------------------------
__global__ __launch_bounds__(256)
void k_gemm(const float* __restrict__ A, const float* __restrict__ B,
            const float* __restrict__ bias, float* __restrict__ C,
            int R, int Cc, int K, int actTanh)
{
    __shared__ __align__(16) float Asm[16][132];
    __shared__ __align__(16) float Bsm[16][132];
    const int tid = threadIdx.x;
    const int r0 = blockIdx.y * 128, c0 = blockIdx.x * 128;
    const int li = tid >> 1, lk = (tid & 1) * 8;
    const int tx = tid & 15, ty = tid >> 4;
    float acc[8][8];
#pragma unroll
    for (int i = 0; i < 8; ++i)
#pragma unroll
        for (int j = 0; j < 8; ++j) acc[i][j] = 0.f;
    const int nch = (K + 15) >> 4;
    for (int ch = 0; ch < nch; ++ch) {
        const int k0 = ch * 16;
        {
            float v[8];
            int gr = r0 + li, kb = k0 + lk;
            if (gr < R && kb + 8 <= K) {
                const float* p = A + (size_t)gr * K + kb;
                *(float4*)&v[0] = *(const float4*)p;
                *(float4*)&v[4] = *(const float4*)(p + 4);
            } else {
#pragma unroll
                for (int z = 0; z < 8; ++z) {
                    int k = kb + z;
                    v[z] = (gr < R && k < K) ? A[(size_t)gr * K + k] : 0.f;
                }
            }
#pragma unroll
            for (int z = 0; z < 8; ++z) Asm[lk + z][li] = v[z];
        }
        {
            float v[8];
            int gr = c0 + li, kb = k0 + lk;
            if (gr < Cc && kb + 8 <= K) {
                const float* p = B + (size_t)gr * K + kb;
                *(float4*)&v[0] = *(const float4*)p;
                *(float4*)&v[4] = *(const float4*)(p + 4);
            } else {
#pragma unroll
                for (int z = 0; z < 8; ++z) {
                    int k = kb + z;
                    v[z] = (gr < Cc && k < K) ? B[(size_t)gr * K + k] : 0.f;
                }
            }
#pragma unroll
            for (int z = 0; z < 8; ++z) Bsm[lk + z][li] = v[z];
        }
        __syncthreads();
#pragma unroll
        for (int kk = 0; kk < 16; ++kk) {
            float a[8], b[8];
            *(float4*)&a[0] = *(const float4*)&Asm[kk][ty * 8];
            *(float4*)&a[4] = *(const float4*)&Asm[kk][ty * 8 + 4];
            *(float4*)&b[0] = *(const float4*)&Bsm[kk][tx * 8];
            *(float4*)&b[4] = *(const float4*)&Bsm[kk][tx * 8 + 4];
#pragma unroll
            for (int i = 0; i < 8; ++i)
#pragma unroll
                for (int j = 0; j < 8; ++j) acc[i][j] = fmaf(a[i], b[j], acc[i][j]);
        }
        __syncthreads();
    }
#pragma unroll
    for (int i = 0; i < 8; ++i) {
        int r = r0 + ty * 8 + i;
        if (r >= R) continue;
#pragma unroll
        for (int j = 0; j < 8; ++j) {
            int c = c0 + tx * 8 + j;
            if (c >= Cc) continue;
            float v = acc[i][j];
            if (bias) v += bias[c];
            if (actTanh) v = tanhf(v);
            C[(size_t)r * Cc + c] = v;
        }
    }
}

// ---------------------------------------------------------------------------
// GRU scan core: 960 threads, thread (p,m) owns 3 gate-rows over cols
// [100p,100p+100). Chunks 0..9 LDS-resident, 10..38 streamed (ring depth 8).
// gi is bf16. h broadcast from LDS.
// ---------------------------------------------------------------------------
template<bool IS_UTT>
__device__ __forceinline__ void gru_scan_body(
    const short* __restrict__ Wp,   // [2][39][912][8sh]
    const float* __restrict__ bhh,
    const short* __restrict__ gi,   // [T*NB][1800] bf16
    int d, int chain, int NB, int len,
    float* __restrict__ outp)       // maxpool row (utt) or hout base (ctx)
{
    extern __shared__ char smem[];
    short* wlds = (short*)smem;                               // [10][912][8]
    float* hs   = (float*)(smem + (size_t)GRU_RES * 912 * 16);// [304]
    float* pds  = hs + 304;                                   // [3][3][300]
    const int tid = threadIdx.x;
    const int p = tid / 300, m = tid - p * 300;  // valid for tid<900
    const uint4* wall = (const uint4*)(Wp + (size_t)d * 39 * 912 * 8);
    if (tid < 912) {
#pragma unroll
        for (int c = 0; c < GRU_RES; ++c)
            *(uint4*)(wlds + ((size_t)c * 912 + tid) * 8) = wall[(size_t)c * 912 + tid];
    }
    if (tid < 304) hs[tid] = 0.f;
    float br = 0.f, bz = 0.f, bn = 0.f;
    if (tid < 300) {
        br = bhh[d * 900 + tid];
        bz = bhh[d * 900 + 300 + tid];
        bn = bhh[d * 900 + 600 + tid];
    }
    float mx = -1e30f;
    __syncthreads();
    for (int t = 0; t < len; ++t) {
        int ts = d ? (len - 1 - t) : t;
        float g0 = 0.f, g1 = 0.f, g2 = 0.f;
        if (tid < 300) {   // prefetch gate inputs (used after the barrier)
            size_t row = ((size_t)(ts * NB + chain)) * 1800 + d * 900 + tid;
            g0 = b2f(gi[row]); g1 = b2f(gi[row + 300]); g2 = b2f(gi[row + 600]);
        }
        if (tid < 900) {
            const int hb = 100 * p;
            float a0 = 0.f, a1 = 0.f, a2 = 0.f;
            uint4 ring[8];
#pragma unroll
            for (int i = 0; i < 8; ++i) ring[i] = wall[(size_t)(GRU_RES + i) * 912 + tid];
            // LDS-resident chunks — overlap ring latency
#pragma unroll
            for (int c = 0; c < GRU_RES; ++c) {
                int cs = c / 3, s = c - 3 * cs;
                float4 h0 = *(const float4*)&hs[hb + 8 * cs];
                float4 h1 = *(const float4*)&hs[hb + 8 * cs + 4];
                uint4 wv = *(const uint4*)(wlds + ((size_t)c * 912 + tid) * 8);
                if (s == 0) dot8(wv, h0, h1, a0);
                else if (s == 1) dot8(wv, h0, h1, a1);
                else dot8(wv, h0, h1, a2);
            }
            // streamed chunks
#pragma unroll
            for (int i = 0; i < 39 - GRU_RES; ++i) {
                int c = GRU_RES + i, cs = c / 3, s = c - 3 * cs;
                uint4 wv = ring[i & 7];
                if (i + 8 < 39 - GRU_RES)
                    ring[i & 7] = wall[(size_t)(c + 8) * 912 + tid];
                float4 h0 = *(const float4*)&hs[hb + 8 * cs];
                float4 h1 = *(const float4*)&hs[hb + 8 * cs + 4];
                if (s == 0) dot8(wv, h0, h1, a0);
                else if (s == 1) dot8(wv, h0, h1, a1);
                else dot8(wv, h0, h1, a2);
            }
            pds[(0 * 3 + p) * 300 + m] = a0;
            pds[(1 * 3 + p) * 300 + m] = a1;
            pds[(2 * 3 + p) * 300 + m] = a2;
        }
        __syncthreads();
        if (tid < 300) {
            float dr = pds[tid] + pds[300 + tid] + pds[600 + tid] + br;
            float dz = pds[900 + tid] + pds[1200 + tid] + pds[1500 + tid] + bz;
            float dn = pds[1800 + tid] + pds[2100 + tid] + pds[2400 + tid] + bn;
            float r = sigm(g0 + dr);
            float z = sigm(g1 + dz);
            float nv = tanhf(g2 + r * dn);
            float hv = (1.f - z) * nv + z * hs[tid];
            hs[tid] = hv;
            if (IS_UTT) mx = fmaxf(mx, hv);
            else outp[(size_t)ts * 300 + tid] = hv;
        }
        __syncthreads();
    }
    if (IS_UTT && tid < 300) {
        if (len < LL) mx = fmaxf(mx, 0.f);   // padded steps contribute 0
        outp[tid] = mx;
    }
}

__global__ __launch_bounds__(960, 1)
void k_utt_scan(const short* __restrict__ Wp, const float* __restrict__ bhh,
                const short* __restrict__ gi, const int* __restrict__ lens,
                float* __restrict__ maxpool)
{
    const int d = blockIdx.y, n = blockIdx.x;
    gru_scan_body<true>(Wp, bhh, gi, d, n, NN, lens[n],
                        maxpool + (size_t)n * 600 + d * 300);
}

__global__ __launch_bounds__(960, 1)
void k_ctx_scan(const short* __restrict__ Wp, const float* __restrict__ bhh,
                const short* __restrict__ gi, float* __restrict__ hout)
{
    const int d = blockIdx.y, q = blockIdx.x;
    gru_scan_body<false>(Wp, bhh, gi, d, q, NQ, KEFF,
                         hout + (((size_t)d * NQ + q) * KEFF) * 300);
}

// ---------------------------------------------------------------------------
// mem_bank f32 [q][k][e] + mrkq bf16 [k*127+q][320] + query0 init (k==0)
// ---------------------------------------------------------------------------
__global__ void k_combine(const float* __restrict__ u, const float* __restrict__ hout,
                          float* __restrict__ mem_bank, short* __restrict__ mrkq,
                          float* __restrict__ query0)
{
    int rkq = blockIdx.x;            // k*127 + q
    int k = rkq / NQ, q = rkq - k * NQ;
    int src = q + 1 - KWIN + k;
    int e = threadIdx.x;             // 320 threads
    float v = 0.f;
    if (e < 300) {
        float c = (src >= 0) ? u[(size_t)src * 300 + e] : 0.f;
        v = c + hout[((size_t)q * KEFF + k) * 300 + e]
              + hout[(((size_t)NQ + q) * KEFF + k) * 300 + e];
        mem_bank[((size_t)q * KEFF + k) * 300 + e] = v;
        if (k == 0) query0[(size_t)q * 300 + e] = u[(size_t)(q + 1) * 300 + e];
    }
    mrkq[(size_t)rkq * KP + e] = f2bf(v);
}

// ---------------------------------------------------------------------------
// AttnGRU scan + fused score/softmax. qv = query0 + sum of previous hops'
// hbuf contributions (race-free: hbuf[j] written by earlier kernels).
// Writes its own h into hbuf[hop*2+d]. Chunks 0..15 LDS-resident, 16..39
// streamed (ring depth 8). xgr/xgw are bf16.
// ---------------------------------------------------------------------------
__global__ __launch_bounds__(640, 1)
void k_att_scan(const short* __restrict__ Wp,     // [6][40][608][8sh]
                const float* __restrict__ burb,   // [6*300]
                const float* __restrict__ bub,    // [6*300]
                const short* __restrict__ xgr,    // [5080][1800] bf16
                const short* __restrict__ xgw,
                const float* __restrict__ query0, // [127][300]
                const float* __restrict__ membank,// [127][40][300]
                float* __restrict__ hbuf,         // [6][127][300]
                int hop)
{
    extern __shared__ char smem[];
    short* wlds  = (short*)smem;                               // [16][608][8]
    float* hs    = (float*)(smem + (size_t)ATT_RES * 608 * 16);// [320]
    float* pds   = hs + 320;                                   // [2][2][304]
    float* qv    = pds + 1216;                                 // [304]
    float* gates = qv + 304;                                   // [40]
    float* scr   = gates + 40;                                 // [40]
    const int d = blockIdx.y, q = blockIdx.x, tid = threadIdx.x;
    const int hd = hop * 2 + d;
    const int p = tid / 300, m = tid - p * 300;   // valid tid<600
    const uint4* wall = (const uint4*)(Wp + (size_t)hd * 40 * 608 * 8);
    if (tid < 608) {
#pragma unroll
        for (int c = 0; c < ATT_RES; ++c)
            *(uint4*)(wlds + ((size_t)c * 608 + tid) * 8) = wall[(size_t)c * 608 + tid];
    }
    if (tid < 320) {
        hs[tid] = 0.f;
        float qq = 0.f;
        if (tid < 300) {
            qq = query0[(size_t)q * 300 + tid];
            for (int j = 0; j < hop; ++j)
                qq += hbuf[((size_t)(2 * j) * NQ + q) * 300 + tid]
                    + hbuf[((size_t)(2 * j + 1) * NQ + q) * 300 + tid];
        }
        qv[tid] = qq;
    }
    float bur = 0.f, bu = 0.f;
    if (tid < 300) { bur = burb[hd * 300 + tid]; bu = bub[hd * 300 + tid]; }
    __syncthreads();
    // ---- fused scores: dot + masked softmax ----
    if (tid < 320) {
        int k = tid >> 3, part = tid & 7;
        const float* mrow = membank + ((size_t)q * KEFF + k) * 300;
        int e0 = part * 38, e1 = e0 + 38 > 300 ? 300 : e0 + 38;
        float acc = 0.f;
        for (int e = e0; e < e1; ++e) acc = fmaf(qv[e], mrow[e], acc);
        acc += __shfl_xor(acc, 1);
        acc += __shfl_xor(acc, 2);
        acc += __shfl_xor(acc, 4);
        if (part == 0) scr[k] = acc;
    }
    __syncthreads();
    if (tid < 64) {
        float s = (tid < KEFF) ? scr[tid] : -1e30f;
        if (tid < KWIN - 1 - q) s = -1e10f;     // zero-padded slots masked
        float mxs = s;
        for (int o = 32; o > 0; o >>= 1) mxs = fmaxf(mxs, __shfl_xor(mxs, o));
        float e = (tid < KEFF) ? __expf(s - mxs) : 0.f;
        float sm = e;
        for (int o = 32; o > 0; o >>= 1) sm += __shfl_xor(sm, o);
        if (tid < KEFF) gates[tid] = e / sm;
    }
    __syncthreads();
    // ---- scan ----
    for (int t = 0; t < KEFF; ++t) {
        int kq = d ? (KEFF - 1 - t) : t;
        float xr = 0.f, xw = 0.f, gt = 0.f;
        if (tid < 300) {
            size_t xi = ((size_t)(kq * NQ + q)) * 1800 + (size_t)hd * 300 + tid;
            xr = b2f(xgr[xi]); xw = b2f(xgw[xi]);
            gt = gates[kq];
        }
        if (tid < 600) {
            const int hb = 160 * p;
            float a0 = 0.f, a1 = 0.f;
            uint4 ring[8];
#pragma unroll
            for (int i = 0; i < 8; ++i) ring[i] = wall[(size_t)(ATT_RES + i) * 608 + tid];
            // LDS-resident chunks
#pragma unroll
            for (int c = 0; c < ATT_RES; ++c) {
                int cs = c >> 1, s = c & 1;
                float4 h0 = *(const float4*)&hs[hb + 8 * cs];
                float4 h1 = *(const float4*)&hs[hb + 8 * cs + 4];
                uint4 wv = *(const uint4*)(wlds + ((size_t)c * 608 + tid) * 8);
                if (s == 0) dot8(wv, h0, h1, a0);
                else dot8(wv, h0, h1, a1);
            }
            // streamed chunks
#pragma unroll
            for (int i = 0; i < 40 - ATT_RES; ++i) {
                int c = ATT_RES + i, cs = c >> 1, s = c & 1;
                uint4 wv = ring[i & 7];
                if (i + 8 < 40 - ATT_RES)
                    ring[i & 7] = wall[(size_t)(c + 8) * 608 + tid];
                float4 h0 = *(const float4*)&hs[hb + 8 * cs];
                float4 h1 = *(const float4*)&hs[hb + 8 * cs + 4];
                if (s == 0) dot8(wv, h0, h1, a0);
                else dot8(wv, h0, h1, a1);
            }
            pds[(0 * 2 + p) * 304 + m] = a0;
            pds[(1 * 2 + p) * 304 + m] = a1;
        }
        __syncthreads();
        if (tid < 300) {
            float dr = pds[tid] + pds[304 + tid] + bur;
            float dw = pds[608 + tid] + pds[912 + tid] + bu;
            float r = sigm(xr + dr);
            float ht = tanhf(xw + r * dw);
            hs[tid] = gt * ht + (1.f - gt) * hs[tid];
        }
        __syncthreads();
    }
    if (tid < 300)
        hbuf[((size_t)hd * NQ + q) * 300 + tid] = hs[tid];
}

// ---------------------------------------------------------------------------
// classifier: s_context[0]=u[0]; s_context[n>=1]=query0[n-1]+sum hbuf[0..5]
// ---------------------------------------------------------------------------
__global__ __launch_bounds__(64)
void k_cls(const float* __restrict__ u, const float* __restrict__ query0,
           const float* __restrict__ hbuf,
           const float* __restrict__ cw, const float* __restrict__ cb,
           float* __restrict__ out)
{
    int n = blockIdx.x;
    int c = threadIdx.x & 7;
    int part = threadIdx.x >> 3;
    float p = 0.f;
    if (c < NCLS) {
        for (int e = part; e < 300; e += 8) {
            float s;
            if (n == 0) s = u[e];
            else {
                int q = n - 1;
                s = query0[(size_t)q * 300 + e];
#pragma unroll
                for (int j = 0; j < 6; ++j)
                    s += hbuf[((size_t)j * NQ + q) * 300 + e];
            }
            p = fmaf(s, cw[c * 300 + e], p);
        }
    }
    p += __shfl_xor(p, 8);
    p += __shfl_xor(p, 16);
    p += __shfl_xor(p, 32);
    if (part == 0 && c < NCLS) out[n * NCLS + c] = p + cb[c];
}

// ---------------------------------------------------------------------------
extern "C" void kernel_launch(void* const* d_in, const int* in_sizes, int n_in,
                              void* d_out, int out_size, void* d_ws, size_t ws_size,
                              hipStream_t stream)
{
    const int* ids  = (const int*)d_in[0];
    const int* lens = (const int*)d_in[1];
    const float* emb   = (const float*)d_in[2];
    const float* uWih  = (const float*)d_in[3];
    const float* uWhh  = (const float*)d_in[4];
    const float* ubih  = (const float*)d_in[5];
    const float* ubhh  = (const float*)d_in[6];
    const float* linw  = (const float*)d_in[7];
    const float* linb  = (const float*)d_in[8];
    const float* cWih  = (const float*)d_in[9];
    const float* cWhh  = (const float*)d_in[10];
    const float* cbih  = (const float*)d_in[11];
    const float* cbhh  = (const float*)d_in[12];
    const float* aWr_w = (const float*)d_in[13];
    const float* aWr_b = (const float*)d_in[14];
    const float* aUr_w = (const float*)d_in[15];
    const float* aUr_b = (const float*)d_in[16];
    const float* aW_w  = (const float*)d_in[17];
    const float* aW_b  = (const float*)d_in[18];
    const float* aU_w  = (const float*)d_in[19];
    const float* aU_b  = (const float*)d_in[20];
    const float* clsw  = (const float*)d_in[21];
    const float* clsb  = (const float*)d_in[22];
    float* out = (float*)d_out;
    (void)in_sizes; (void)n_in; (void)out_size; (void)ws_size;

    // opt-in to >64KB dynamic LDS
    (void)hipFuncSetAttribute((const void*)k_utt_scan,
            hipFuncAttributeMaxDynamicSharedMemorySize, (int)GRU_LDS);
    (void)hipFuncSetAttribute((const void*)k_ctx_scan,
            hipFuncAttributeMaxDynamicSharedMemorySize, (int)GRU_LDS);
    (void)hipFuncSetAttribute((const void*)k_att_scan,
            hipFuncAttributeMaxDynamicSharedMemorySize, (int)ATT_LDS);

    char* base = (char*)d_ws;
    size_t off = 0;
    auto alloc = [&](size_t b) -> void* {
        void* r = (void*)(base + off);
        off += (b + 255) & ~(size_t)255;
        return r;
    };
    short* giU    = (short*)alloc((size_t)8192 * 1800 * 2);        // 29.5 MB (reused: xgr)
    short* giC    = (short*)alloc((size_t)5080 * 1800 * 2);        // 18.3 MB (reused: xgw)
    short* wUihB  = (short*)alloc((size_t)1800 * KP * 2);
    short* wCihB  = (short*)alloc((size_t)1800 * KP * 2);
    short* wArB   = (short*)alloc((size_t)1800 * KP * 2);
    short* wAwB   = (short*)alloc((size_t)1800 * KP * 2);
    short* wPackU = (short*)alloc((size_t)2 * 39 * 912 * 8 * 2);   // 1.14 MB
    short* wPackC = (short*)alloc((size_t)2 * 39 * 912 * 8 * 2);
    short* wPackA = (short*)alloc((size_t)6 * 40 * 608 * 8 * 2);   // 2.33 MB
    float* hout   = (float*)alloc((size_t)2 * NQ * KEFF * 300 * 4);
    float* membank= (float*)alloc((size_t)NQ * KEFF * 300 * 4);
    short* mrkq   = (short*)alloc((size_t)5080 * KP * 2);
    float* mpool  = (float*)alloc((size_t)NN * 600 * 4);
    float* uu     = (float*)alloc((size_t)NN * 300 * 4);
    float* query0 = (float*)alloc((size_t)NQ * 300 * 4);
    float* hbuf   = (float*)alloc((size_t)6 * NQ * 300 * 4);
    short* xgr = giU;   // giU dead after k_utt_scan
    short* xgw = giC;   // giC dead after k_ctx_scan

    const int RKQ = NQ * KEFF;  // 5080

    // 0) weight conversions / packing (fused launches)
    k_conv4<<<dim3(1800, 4), dim3(320), 0, stream>>>(uWih, cWih, aWr_w, aW_w,
                                                     wUihB, wCihB, wArB, wAwB);
    k_pack_gru2<<<dim3((2 * 39 * 900 + 255) / 256, 2), dim3(256), 0, stream>>>(
        uWhh, cWhh, wPackU, wPackC);
    k_pack_att<<<dim3((6 * 40 * 600 + 255) / 256), dim3(256), 0, stream>>>(aUr_w, aU_w, wPackA);

    // 1) utt input-gate GEMM (gather fused), 2) utt scan + maxpool
    k_mgemm<1><<<dim3(15, 64, 1), dim3(256), 0, stream>>>(
        nullptr, emb, ids, nullptr, wUihB, ubih, giU,
        wUihB, ubih, giU, 8192, 1800);
    k_utt_scan<<<dim3(NN, 2), dim3(960), GRU_LDS, stream>>>(wPackU, ubhh, giU, lens, mpool);
    // 3) u = tanh(maxpool @ lin_w.T + lin_b)
    k_gemm<<<dim3(3, 1), dim3(256), 0, stream>>>(mpool, linw, linb, uu, NN, 300, 600, 1);
    // 4) ctx input-gate GEMM (window build fused) + ctx scan + combine
    k_mgemm<2><<<dim3(15, 40, 1), dim3(256), 0, stream>>>(
        nullptr, nullptr, nullptr, uu, wCihB, cbih, giC,
        wCihB, cbih, giC, RKQ, 1800);
    k_ctx_scan<<<dim3(NQ, 2), dim3(960), GRU_LDS, stream>>>(wPackC, cbhh, giC, hout);
    k_combine<<<dim3(RKQ), dim3(320), 0, stream>>>(uu, hout, membank, mrkq, query0);
    // 5) both attention x-projections in one launch (z selects)
    k_mgemm<0><<<dim3(15, 40, 2), dim3(256), 0, stream>>>(
        mrkq, nullptr, nullptr, nullptr, wArB, aWr_b, xgr,
        wAwB, aW_b, xgw, RKQ, 1800);
    // 6) hops (scores + query accumulation fused; no qupd kernels)
    for (int hop = 0; hop < 3; ++hop) {
        k_att_scan<<<dim3(NQ, 2), dim3(640), ATT_LDS, stream>>>(
            wPackA, aUr_b, aU_b, xgr, xgw, query0, membank, hbuf, hop);
    }
    // 7) classifier
    k_cls<<<dim3(NN), dim3(64), 0, stream>>>(uu, query0, hbuf, clsw, clsb, out);
}